// Round 1
// baseline (569.416 us; speedup 1.0000x reference)
//
#include <hip/hip_runtime.h>
#include <math.h>

#define IMG_W 512
#define IMG_H 512
#define NB 32
#define NC 3

// ws layout: ws[0..31] = num[b], ws[32..63] = den[b]

__global__ __launch_bounds__(256) void recon_main(
    const float* __restrict__ theta,
    const float* __restrict__ img_R,
    const float* __restrict__ img_orig,
    float* __restrict__ ws)
{
    const int b = blockIdx.y;
    const int p = blockIdx.x * 256 + threadIdx.x;
    const int h = p >> 9;          // p / 512
    const int w = p & 511;         // p % 512

    // --- per-batch affine (wave-uniform; theta loads hit cache/sgpr) ---
    const float ang   = theta[b * 3 + 0];
    const float s     = theta[b * 3 + 1];
    const float shift = 100.0f * theta[b * 3 + 2];
    float sn, cs;
    sincosf(ang, &sn, &cs);
    const float alpha = s * cs;
    const float beta  = s * sn;
    // cv matrix, cx=cy=256
    const float tx = (1.0f - alpha) * 256.0f - beta * 256.0f + shift;
    const float ty = beta * 256.0f + (1.0f - alpha) * 256.0f;
    // normalized transform (sw == sh == 511 -> ratios are 1)
    const float A  = alpha;
    const float Bc = beta;
    const float Cc = alpha + beta + 2.0f * tx / 511.0f - 1.0f;
    const float D  = -beta;
    const float E  = alpha;
    const float Fc = -beta + alpha + 2.0f * ty / 511.0f - 1.0f;

    // --- grid coordinate for this pixel ---
    const float u = (float)w * (2.0f / 511.0f) - 1.0f;
    const float v = (float)h * (2.0f / 511.0f) - 1.0f;
    const float gx = A * u + Bc * v + Cc;
    const float gy = D * u + E * v + Fc;
    const float x = (gx + 1.0f) * 255.5f;
    const float y = (gy + 1.0f) * 255.5f;

    const float x0f = floorf(x);
    const float y0f = floorf(y);
    const float wx1 = x - x0f, wy1 = y - y0f;
    const float wx0 = 1.0f - wx1, wy0 = 1.0f - wy1;
    const float x1f = x0f + 1.0f, y1f = y0f + 1.0f;

    const float vx0 = (x0f >= 0.0f && x0f < (float)IMG_W) ? 1.0f : 0.0f;
    const float vx1 = (x1f >= 0.0f && x1f < (float)IMG_W) ? 1.0f : 0.0f;
    const float vy0 = (y0f >= 0.0f && y0f < (float)IMG_H) ? 1.0f : 0.0f;
    const float vy1 = (y1f >= 0.0f && y1f < (float)IMG_H) ? 1.0f : 0.0f;

    const int xi0 = (int)fminf(fmaxf(x0f, 0.0f), 511.0f);
    const int xi1 = (int)fminf(fmaxf(x1f, 0.0f), 511.0f);
    const int yi0 = (int)fminf(fmaxf(y0f, 0.0f), 511.0f);
    const int yi1 = (int)fminf(fmaxf(y1f, 0.0f), 511.0f);

    const float w00 = wx0 * wy0 * vx0 * vy0;
    const float w10 = wx1 * wy0 * vx1 * vy0;
    const float w01 = wx0 * wy1 * vx0 * vy1;
    const float w11 = wx1 * wy1 * vx1 * vy1;

    const float mask = w00 + w10 + w01 + w11;

    const size_t img_base = (size_t)b * NC * IMG_H * IMG_W;
    const float* orig_b = img_orig + img_base;
    const float* R_b    = img_R + img_base;

    float nrm = 0.0f;
#pragma unroll
    for (int c = 0; c < NC; ++c) {
        const float* plane = orig_b + (size_t)c * IMG_H * IMG_W;
        const float s00 = plane[yi0 * IMG_W + xi0];
        const float s10 = plane[yi0 * IMG_W + xi1];
        const float s01 = plane[yi1 * IMG_W + xi0];
        const float s11 = plane[yi1 * IMG_W + xi1];
        const float warped = s00 * w00 + s10 * w10 + s01 * w01 + s11 * w11;
        const float r = R_b[(size_t)c * IMG_H * IMG_W + p];
        nrm += fabsf(r - warped);
    }

    float num_p = mask * nrm;
    float den_p = mask;

    // --- wave (64) reduction ---
#pragma unroll
    for (int off = 32; off > 0; off >>= 1) {
        num_p += __shfl_down(num_p, off);
        den_p += __shfl_down(den_p, off);
    }

    __shared__ float snum[4];
    __shared__ float sden[4];
    const int wave = threadIdx.x >> 6;
    const int lane = threadIdx.x & 63;
    if (lane == 0) { snum[wave] = num_p; sden[wave] = den_p; }
    __syncthreads();
    if (threadIdx.x == 0) {
        const float n = snum[0] + snum[1] + snum[2] + snum[3];
        const float d = sden[0] + sden[1] + sden[2] + sden[3];
        atomicAdd(&ws[b], n);
        atomicAdd(&ws[NB + b], d);
    }
}

__global__ __launch_bounds__(64) void recon_final(
    const float* __restrict__ ws,
    float* __restrict__ out)
{
    const int t = threadIdx.x;
    float loss = 0.0f;
    if (t < NB) {
        loss = 10.0f * (ws[t] + 1e-16f) / (ws[NB + t] + 1e-16f);
    }
#pragma unroll
    for (int off = 32; off > 0; off >>= 1) {
        loss += __shfl_down(loss, off);
    }
    if (t == 0) out[0] = loss * (1.0f / (float)NB);
}

extern "C" void kernel_launch(void* const* d_in, const int* in_sizes, int n_in,
                              void* d_out, int out_size, void* d_ws, size_t ws_size,
                              hipStream_t stream) {
    const float* theta    = (const float*)d_in[0];
    const float* img_R    = (const float*)d_in[1];
    const float* img_orig = (const float*)d_in[2];
    float* out = (float*)d_out;
    float* ws  = (float*)d_ws;

    hipMemsetAsync(ws, 0, 2 * NB * sizeof(float), stream);

    dim3 grid((IMG_H * IMG_W) / 256, NB);
    recon_main<<<grid, 256, 0, stream>>>(theta, img_R, img_orig, ws);
    recon_final<<<1, 64, 0, stream>>>(ws, out);
}

// Round 2
// 407.536 us; speedup vs baseline: 1.3972x; 1.3972x over previous
//
#include <hip/hip_runtime.h>
#include <math.h>

#define IMG_W 512
#define IMG_H 512
#define NB 32
#define NC 3
#define PLANE (IMG_H * IMG_W)          // 262144 px per channel
#define CHUNKS_X 32                    // blocks per batch
#define PX_PER_BLOCK (PLANE / CHUNKS_X)   // 8192
#define PX_PER_ITER (256 * 4)          // 1024
#define NITER (PX_PER_BLOCK / PX_PER_ITER) // 8

// ws layout: ws[0..31] = num[b], ws[32..63] = den[b]

__global__ __launch_bounds__(256) void recon_main(
    const float* __restrict__ theta,
    const float* __restrict__ img_R,
    const float* __restrict__ img_orig,
    float* __restrict__ ws)
{
    const int b   = blockIdx.y;
    const int tid = threadIdx.x;

    // --- per-batch affine (uniform across block) ---
    const float ang   = theta[b * 3 + 0];
    const float s     = theta[b * 3 + 1];
    const float shift = 100.0f * theta[b * 3 + 2];
    float sn, cs;
    sincosf(ang, &sn, &cs);
    const float alpha = s * cs;
    const float beta  = s * sn;
    const float tx = (1.0f - alpha) * 256.0f - beta * 256.0f + shift;
    const float ty = beta * 256.0f + (1.0f - alpha) * 256.0f;
    const float Cc = alpha + beta + 2.0f * tx / 511.0f - 1.0f;
    const float Fc = -beta + alpha + 2.0f * ty / 511.0f - 1.0f;
    // source coords: x = X0 + alpha*w + beta*h ; y = Y0 - beta*w + alpha*h
    const float X0 = 255.5f * (Cc + 1.0f - alpha - beta);
    const float Y0 = 255.5f * (Fc + 1.0f + beta - alpha);

    const float* orig_b = img_orig + (size_t)b * NC * PLANE;
    const float* R_b    = img_R    + (size_t)b * NC * PLANE;

    float num_acc = 0.0f, den_acc = 0.0f;

    const int base = blockIdx.x * PX_PER_BLOCK;

    for (int it = 0; it < NITER; ++it) {
        const int p0 = base + it * PX_PER_ITER + tid * 4;
        const int h  = p0 >> 9;
        const int w0 = p0 & 511;           // w0..w0+3 stay in-row (p0 % 4 == 0)

        const float xb = X0 + alpha * (float)w0 + beta * (float)h;
        const float yb = Y0 - beta * (float)w0 + alpha * (float)h;

        int   a0[4], a1[4], sl0[4], sl1[4];
        float w00[4], w10[4], w01[4], w11[4], mk[4];

#pragma unroll
        for (int j = 0; j < 4; ++j) {
            const float x = xb + alpha * (float)j;
            const float y = yb - beta  * (float)j;
            const float x0f = floorf(x), y0f = floorf(y);
            const float fx1 = x - x0f,  fy1 = y - y0f;
            const float fx0 = 1.0f - fx1, fy0 = 1.0f - fy1;
            const float vx0 = (x0f >=  0.0f && x0f <= 511.0f) ? 1.0f : 0.0f;
            const float vx1 = (x0f >= -1.0f && x0f <= 510.0f) ? 1.0f : 0.0f;
            const float vy0 = (y0f >=  0.0f && y0f <= 511.0f) ? 1.0f : 0.0f;
            const float vy1 = (y0f >= -1.0f && y0f <= 510.0f) ? 1.0f : 0.0f;
            const int xi0 = (int)fminf(fmaxf(x0f,        0.0f), 511.0f);
            const int xi1 = (int)fminf(fmaxf(x0f + 1.0f, 0.0f), 511.0f);
            const int yi0 = (int)fminf(fmaxf(y0f,        0.0f), 511.0f);
            const int yi1 = (int)fminf(fmaxf(y0f + 1.0f, 0.0f), 511.0f);
            const int xc  = min(xi0, 510);      // float2 base; xi0,xi1 in {xc, xc+1}
            w00[j] = fx0 * fy0 * vx0 * vy0;
            w10[j] = fx1 * fy0 * vx1 * vy0;
            w01[j] = fx0 * fy1 * vx0 * vy1;
            w11[j] = fx1 * fy1 * vx1 * vy1;
            mk[j]  = w00[j] + w10[j] + w01[j] + w11[j];
            a0[j]  = yi0 * IMG_W + xc;
            a1[j]  = yi1 * IMG_W + xc;
            sl0[j] = xi0 - xc;                  // 0 or 1
            sl1[j] = xi1 - xc;
            den_acc += mk[j];
        }

        float nrm[4] = {0.0f, 0.0f, 0.0f, 0.0f};
#pragma unroll
        for (int c = 0; c < NC; ++c) {
            const float* plane = orig_b + c * PLANE;
            const float4 rv = *(const float4*)(R_b + c * PLANE + p0);
            const float rj[4] = {rv.x, rv.y, rv.z, rv.w};
#pragma unroll
            for (int j = 0; j < 4; ++j) {
                const float2 t0 = *(const float2*)(plane + a0[j]);
                const float2 t1 = *(const float2*)(plane + a1[j]);
                const float s00 = sl0[j] ? t0.y : t0.x;
                const float s10 = sl1[j] ? t0.y : t0.x;
                const float s01 = sl0[j] ? t1.y : t1.x;
                const float s11 = sl1[j] ? t1.y : t1.x;
                const float warped = s00 * w00[j] + s10 * w10[j]
                                   + s01 * w01[j] + s11 * w11[j];
                nrm[j] += fabsf(rj[j] - warped);
            }
        }
#pragma unroll
        for (int j = 0; j < 4; ++j) num_acc += mk[j] * nrm[j];
    }

    // --- wave (64) reduction ---
#pragma unroll
    for (int off = 32; off > 0; off >>= 1) {
        num_acc += __shfl_down(num_acc, off);
        den_acc += __shfl_down(den_acc, off);
    }

    __shared__ float snum[4];
    __shared__ float sden[4];
    const int wave = threadIdx.x >> 6;
    const int lane = threadIdx.x & 63;
    if (lane == 0) { snum[wave] = num_acc; sden[wave] = den_acc; }
    __syncthreads();
    if (threadIdx.x == 0) {
        const float n = snum[0] + snum[1] + snum[2] + snum[3];
        const float d = sden[0] + sden[1] + sden[2] + sden[3];
        atomicAdd(&ws[b], n);
        atomicAdd(&ws[NB + b], d);
    }
}

__global__ __launch_bounds__(64) void recon_final(
    const float* __restrict__ ws,
    float* __restrict__ out)
{
    const int t = threadIdx.x;
    float loss = 0.0f;
    if (t < NB) {
        loss = 10.0f * (ws[t] + 1e-16f) / (ws[NB + t] + 1e-16f);
    }
#pragma unroll
    for (int off = 32; off > 0; off >>= 1) {
        loss += __shfl_down(loss, off);
    }
    if (t == 0) out[0] = loss * (1.0f / (float)NB);
}

extern "C" void kernel_launch(void* const* d_in, const int* in_sizes, int n_in,
                              void* d_out, int out_size, void* d_ws, size_t ws_size,
                              hipStream_t stream) {
    const float* theta    = (const float*)d_in[0];
    const float* img_R    = (const float*)d_in[1];
    const float* img_orig = (const float*)d_in[2];
    float* out = (float*)d_out;
    float* ws  = (float*)d_ws;

    hipMemsetAsync(ws, 0, 2 * NB * sizeof(float), stream);

    dim3 grid(CHUNKS_X, NB);
    recon_main<<<grid, 256, 0, stream>>>(theta, img_R, img_orig, ws);
    recon_final<<<1, 64, 0, stream>>>(ws, out);
}

// Round 4
// 276.957 us; speedup vs baseline: 2.0560x; 1.4715x over previous
//
#include <hip/hip_runtime.h>
#include <math.h>

#define IMG_W 512
#define IMG_H 512
#define NB 32
#define NC 3
#define PLANE (IMG_H * IMG_W)      // 262144 px per channel

#define TILE_W 64
#define TILE_H 64
#define TILES_X (IMG_W / TILE_W)   // 8
#define TILES_Y (IMG_H / TILE_H)   // 8
#define TILES_PER_B (TILES_X * TILES_Y)  // 64
#define NBLOCKS (NB * TILES_PER_B)       // 2048
#define NITER 4                    // 256 thr * 4 px * 4 iter = 4096 px = 64x64

typedef float vfloat4 __attribute__((ext_vector_type(4)));

// ws layout: ws[0..31] = num[b], ws[32..63] = den[b]

__global__ __launch_bounds__(256) void recon_main(
    const float* __restrict__ theta,
    const float* __restrict__ img_R,
    const float* __restrict__ img_orig,
    float* __restrict__ ws)
{
    // --- XCD-aware decode: same batch -> same XCD (lin%8) ---
    const int lin = blockIdx.x;        // 0..2047
    const int xcd = lin & 7;
    const int loc = lin >> 3;          // 0..255
    const int b   = xcd * 4 + (loc >> 6);   // 0..31
    const int tile = loc & 63;         // 0..63
    const int tx = (tile & (TILES_X - 1)) * TILE_W;
    const int ty = (tile >> 3) * TILE_H;

    const int tid = threadIdx.x;
    const int trow = tid >> 4;         // 0..15 (16 threads per tile row)
    const int tcol = (tid & 15) * 4;   // 0..60

    // --- per-batch affine (uniform across block) ---
    const float ang   = theta[b * 3 + 0];
    const float s     = theta[b * 3 + 1];
    const float shift = 100.0f * theta[b * 3 + 2];
    float sn, cs;
    sincosf(ang, &sn, &cs);
    const float alpha = s * cs;
    const float beta  = s * sn;
    const float tx_a = (1.0f - alpha) * 256.0f - beta * 256.0f + shift;
    const float ty_a = beta * 256.0f + (1.0f - alpha) * 256.0f;
    const float Cc = alpha + beta + 2.0f * tx_a / 511.0f - 1.0f;
    const float Fc = -beta + alpha + 2.0f * ty_a / 511.0f - 1.0f;
    // source coords: x = X0 + alpha*w + beta*h ; y = Y0 - beta*w + alpha*h
    const float X0 = 255.5f * (Cc + 1.0f - alpha - beta);
    const float Y0 = 255.5f * (Fc + 1.0f + beta - alpha);

    const float* orig_b = img_orig + (size_t)b * NC * PLANE;
    const float* R_b    = img_R    + (size_t)b * NC * PLANE;

    float num_acc = 0.0f, den_acc = 0.0f;

    for (int it = 0; it < NITER; ++it) {
        const int h  = ty + it * 16 + trow;
        const int w0 = tx + tcol;
        const int p0 = h * IMG_W + w0;

        const float xb = X0 + alpha * (float)w0 + beta * (float)h;
        const float yb = Y0 - beta * (float)w0 + alpha * (float)h;

        int   a0[4], a1[4], sl0[4], sl1[4];
        float w00[4], w10[4], w01[4], w11[4], mk[4];

#pragma unroll
        for (int j = 0; j < 4; ++j) {
            const float x = xb + alpha * (float)j;
            const float y = yb - beta  * (float)j;
            const float x0f = floorf(x), y0f = floorf(y);
            const float fx1 = x - x0f,  fy1 = y - y0f;
            const float fx0 = 1.0f - fx1, fy0 = 1.0f - fy1;
            const float vx0 = (x0f >=  0.0f && x0f <= 511.0f) ? 1.0f : 0.0f;
            const float vx1 = (x0f >= -1.0f && x0f <= 510.0f) ? 1.0f : 0.0f;
            const float vy0 = (y0f >=  0.0f && y0f <= 511.0f) ? 1.0f : 0.0f;
            const float vy1 = (y0f >= -1.0f && y0f <= 510.0f) ? 1.0f : 0.0f;
            const int xi0 = (int)fminf(fmaxf(x0f,        0.0f), 511.0f);
            const int xi1 = (int)fminf(fmaxf(x0f + 1.0f, 0.0f), 511.0f);
            const int yi0 = (int)fminf(fmaxf(y0f,        0.0f), 511.0f);
            const int yi1 = (int)fminf(fmaxf(y0f + 1.0f, 0.0f), 511.0f);
            const int xc  = min(xi0, 510);      // float2 base; xi0,xi1 in {xc, xc+1}
            w00[j] = fx0 * fy0 * vx0 * vy0;
            w10[j] = fx1 * fy0 * vx1 * vy0;
            w01[j] = fx0 * fy1 * vx0 * vy1;
            w11[j] = fx1 * fy1 * vx1 * vy1;
            mk[j]  = w00[j] + w10[j] + w01[j] + w11[j];
            a0[j]  = yi0 * IMG_W + xc;
            a1[j]  = yi1 * IMG_W + xc;
            sl0[j] = xi0 - xc;                  // 0 or 1
            sl1[j] = xi1 - xc;
            den_acc += mk[j];
        }

        float nrm[4] = {0.0f, 0.0f, 0.0f, 0.0f};
#pragma unroll
        for (int c = 0; c < NC; ++c) {
            const float* plane = orig_b + c * PLANE;
            const vfloat4 rv = __builtin_nontemporal_load(
                                 (const vfloat4*)(R_b + c * PLANE + p0));
            const float rj[4] = {rv.x, rv.y, rv.z, rv.w};
#pragma unroll
            for (int j = 0; j < 4; ++j) {
                const float2 t0 = *(const float2*)(plane + a0[j]);
                const float2 t1 = *(const float2*)(plane + a1[j]);
                const float s00 = sl0[j] ? t0.y : t0.x;
                const float s10 = sl1[j] ? t0.y : t0.x;
                const float s01 = sl0[j] ? t1.y : t1.x;
                const float s11 = sl1[j] ? t1.y : t1.x;
                const float warped = s00 * w00[j] + s10 * w10[j]
                                   + s01 * w01[j] + s11 * w11[j];
                nrm[j] += fabsf(rj[j] - warped);
            }
        }
#pragma unroll
        for (int j = 0; j < 4; ++j) num_acc += mk[j] * nrm[j];
    }

    // --- wave (64) reduction ---
#pragma unroll
    for (int off = 32; off > 0; off >>= 1) {
        num_acc += __shfl_down(num_acc, off);
        den_acc += __shfl_down(den_acc, off);
    }

    __shared__ float snum[4];
    __shared__ float sden[4];
    const int wave = threadIdx.x >> 6;
    const int lane = threadIdx.x & 63;
    if (lane == 0) { snum[wave] = num_acc; sden[wave] = den_acc; }
    __syncthreads();
    if (threadIdx.x == 0) {
        const float n = snum[0] + snum[1] + snum[2] + snum[3];
        const float d = sden[0] + sden[1] + sden[2] + sden[3];
        atomicAdd(&ws[b], n);
        atomicAdd(&ws[NB + b], d);
    }
}

__global__ __launch_bounds__(64) void recon_final(
    const float* __restrict__ ws,
    float* __restrict__ out)
{
    const int t = threadIdx.x;
    float loss = 0.0f;
    if (t < NB) {
        loss = 10.0f * (ws[t] + 1e-16f) / (ws[NB + t] + 1e-16f);
    }
#pragma unroll
    for (int off = 32; off > 0; off >>= 1) {
        loss += __shfl_down(loss, off);
    }
    if (t == 0) out[0] = loss * (1.0f / (float)NB);
}

extern "C" void kernel_launch(void* const* d_in, const int* in_sizes, int n_in,
                              void* d_out, int out_size, void* d_ws, size_t ws_size,
                              hipStream_t stream) {
    const float* theta    = (const float*)d_in[0];
    const float* img_R    = (const float*)d_in[1];
    const float* img_orig = (const float*)d_in[2];
    float* out = (float*)d_out;
    float* ws  = (float*)d_ws;

    (void)hipMemsetAsync(ws, 0, 2 * NB * sizeof(float), stream);

    recon_main<<<NBLOCKS, 256, 0, stream>>>(theta, img_R, img_orig, ws);
    recon_final<<<1, 64, 0, stream>>>(ws, out);
}

// Round 5
// 258.536 us; speedup vs baseline: 2.2025x; 1.0712x over previous
//
#include <hip/hip_runtime.h>
#include <math.h>

#define IMG_W 512
#define IMG_H 512
#define NB 32
#define NC 3
#define PLANE (IMG_H * IMG_W)      // 262144 px per channel

#define TILE_W 32
#define TILE_H 32
#define TILES_X (IMG_W / TILE_W)   // 16
#define TILES_Y (IMG_H / TILE_H)   // 16
#define TILES_PER_B (TILES_X * TILES_Y)  // 256
#define NBLOCKS (NB * TILES_PER_B)       // 8192

typedef float vfloat4 __attribute__((ext_vector_type(4)));

// ws layout: ws[lin] = num of block lin, ws[NBLOCKS + lin] = den of block lin.
// lin = ((b&3)*256 + tile)*8 + (b>>2)   (XCD swizzle: lin&7 selects XCD)

__global__ __launch_bounds__(256) void recon_main(
    const float* __restrict__ theta,
    const float* __restrict__ img_R,
    const float* __restrict__ img_orig,
    float* __restrict__ ws)
{
    // --- XCD-aware decode: same batch -> same XCD (lin%8) ---
    const int lin = blockIdx.x;        // 0..8191
    const int xcd = lin & 7;
    const int loc = lin >> 3;          // 0..1023
    const int b   = xcd * 4 + (loc >> 8);   // 0..31
    const int tile = loc & 255;        // 0..255
    const int tx = (tile & (TILES_X - 1)) * TILE_W;
    const int ty = (tile >> 4) * TILE_H;

    const int tid  = threadIdx.x;
    const int trow = tid >> 3;         // 0..31 (8 threads per tile row)
    const int tcol = (tid & 7) * 4;    // 0..28

    // --- per-batch affine (uniform across block) ---
    const float ang   = theta[b * 3 + 0];
    const float s     = theta[b * 3 + 1];
    const float shift = 100.0f * theta[b * 3 + 2];
    float sn, cs;
    sincosf(ang, &sn, &cs);
    const float alpha = s * cs;
    const float beta  = s * sn;
    const float tx_a = (1.0f - alpha) * 256.0f - beta * 256.0f + shift;
    const float ty_a = beta * 256.0f + (1.0f - alpha) * 256.0f;
    const float Cc = alpha + beta + 2.0f * tx_a / 511.0f - 1.0f;
    const float Fc = -beta + alpha + 2.0f * ty_a / 511.0f - 1.0f;
    // source coords: x = X0 + alpha*w + beta*h ; y = Y0 - beta*w + alpha*h
    const float X0 = 255.5f * (Cc + 1.0f - alpha - beta);
    const float Y0 = 255.5f * (Fc + 1.0f + beta - alpha);

    const float* orig_b = img_orig + (size_t)b * NC * PLANE;
    const float* R_b    = img_R    + (size_t)b * NC * PLANE;

    const int h  = ty + trow;
    const int w0 = tx + tcol;
    const int p0 = h * IMG_W + w0;

    const float xb = X0 + alpha * (float)w0 + beta * (float)h;
    const float yb = Y0 - beta * (float)w0 + alpha * (float)h;

    int   a0[4], a1[4], sl0[4], sl1[4];
    float w00[4], w10[4], w01[4], w11[4], mk[4];
    float den_acc = 0.0f;

#pragma unroll
    for (int j = 0; j < 4; ++j) {
        const float x = xb + alpha * (float)j;
        const float y = yb - beta  * (float)j;
        const float x0f = floorf(x), y0f = floorf(y);
        const float fx1 = x - x0f,  fy1 = y - y0f;
        const float fx0 = 1.0f - fx1, fy0 = 1.0f - fy1;
        const float vx0 = (x0f >=  0.0f && x0f <= 511.0f) ? 1.0f : 0.0f;
        const float vx1 = (x0f >= -1.0f && x0f <= 510.0f) ? 1.0f : 0.0f;
        const float vy0 = (y0f >=  0.0f && y0f <= 511.0f) ? 1.0f : 0.0f;
        const float vy1 = (y0f >= -1.0f && y0f <= 510.0f) ? 1.0f : 0.0f;
        const int xi0 = (int)fminf(fmaxf(x0f,        0.0f), 511.0f);
        const int xi1 = (int)fminf(fmaxf(x0f + 1.0f, 0.0f), 511.0f);
        const int yi0 = (int)fminf(fmaxf(y0f,        0.0f), 511.0f);
        const int yi1 = (int)fminf(fmaxf(y0f + 1.0f, 0.0f), 511.0f);
        const int xc  = min(xi0, 510);      // float2 base; xi0,xi1 in {xc, xc+1}
        w00[j] = fx0 * fy0 * vx0 * vy0;
        w10[j] = fx1 * fy0 * vx1 * vy0;
        w01[j] = fx0 * fy1 * vx0 * vy1;
        w11[j] = fx1 * fy1 * vx1 * vy1;
        mk[j]  = w00[j] + w10[j] + w01[j] + w11[j];
        a0[j]  = yi0 * IMG_W + xc;
        a1[j]  = yi1 * IMG_W + xc;
        sl0[j] = xi0 - xc;                  // 0 or 1
        sl1[j] = xi1 - xc;
        den_acc += mk[j];
    }

    float nrm[4] = {0.0f, 0.0f, 0.0f, 0.0f};
#pragma unroll
    for (int c = 0; c < NC; ++c) {
        const float* plane = orig_b + c * PLANE;
        const vfloat4 rv = __builtin_nontemporal_load(
                             (const vfloat4*)(R_b + c * PLANE + p0));
        const float rj[4] = {rv.x, rv.y, rv.z, rv.w};
#pragma unroll
        for (int j = 0; j < 4; ++j) {
            const float2 t0 = *(const float2*)(plane + a0[j]);
            const float2 t1 = *(const float2*)(plane + a1[j]);
            const float s00 = sl0[j] ? t0.y : t0.x;
            const float s10 = sl1[j] ? t0.y : t0.x;
            const float s01 = sl0[j] ? t1.y : t1.x;
            const float s11 = sl1[j] ? t1.y : t1.x;
            const float warped = s00 * w00[j] + s10 * w10[j]
                               + s01 * w01[j] + s11 * w11[j];
            nrm[j] += fabsf(rj[j] - warped);
        }
    }
    float num_acc = 0.0f;
#pragma unroll
    for (int j = 0; j < 4; ++j) num_acc += mk[j] * nrm[j];

    // --- wave (64) reduction ---
#pragma unroll
    for (int off = 32; off > 0; off >>= 1) {
        num_acc += __shfl_down(num_acc, off);
        den_acc += __shfl_down(den_acc, off);
    }

    __shared__ float snum[4];
    __shared__ float sden[4];
    const int wave = threadIdx.x >> 6;
    const int lane = threadIdx.x & 63;
    if (lane == 0) { snum[wave] = num_acc; sden[wave] = den_acc; }
    __syncthreads();
    if (threadIdx.x == 0) {
        ws[lin]           = snum[0] + snum[1] + snum[2] + snum[3];
        ws[NBLOCKS + lin] = sden[0] + sden[1] + sden[2] + sden[3];
    }
}

__global__ __launch_bounds__(256) void recon_final(
    const float* __restrict__ ws,
    float* __restrict__ out)
{
    __shared__ float sloss[NB];
    const int t = threadIdx.x;
    const int b = t >> 3;              // 0..31 (8 threads per batch)
    const int j = t & 7;               // 0..7

    float n = 0.0f, d = 0.0f;
    for (int k = 0; k < 32; ++k) {
        const int tile = j * 32 + k;
        const int lin  = ((b & 3) * 256 + tile) * 8 + (b >> 2);
        n += ws[lin];
        d += ws[NBLOCKS + lin];
    }
    // reduce within each 8-lane group (groups are lane-contiguous)
#pragma unroll
    for (int off = 4; off > 0; off >>= 1) {
        n += __shfl_down(n, off);
        d += __shfl_down(d, off);
    }
    if (j == 0) sloss[b] = 10.0f * (n + 1e-16f) / (d + 1e-16f);
    __syncthreads();
    if (t == 0) {
        float L = 0.0f;
#pragma unroll
        for (int i = 0; i < NB; ++i) L += sloss[i];
        out[0] = L * (1.0f / (float)NB);
    }
}

extern "C" void kernel_launch(void* const* d_in, const int* in_sizes, int n_in,
                              void* d_out, int out_size, void* d_ws, size_t ws_size,
                              hipStream_t stream) {
    const float* theta    = (const float*)d_in[0];
    const float* img_R    = (const float*)d_in[1];
    const float* img_orig = (const float*)d_in[2];
    float* out = (float*)d_out;
    float* ws  = (float*)d_ws;

    recon_main<<<NBLOCKS, 256, 0, stream>>>(theta, img_R, img_orig, ws);
    recon_final<<<1, 256, 0, stream>>>(ws, out);
}

// Round 6
// 252.974 us; speedup vs baseline: 2.2509x; 1.0220x over previous
//
#include <hip/hip_runtime.h>
#include <math.h>

#define IMG_W 512
#define IMG_H 512
#define NB 32
#define NC 3
#define PLANE (IMG_H * IMG_W)      // 262144 px per channel

#define TILE_W 32
#define TILE_H 32
#define TILES_X (IMG_W / TILE_W)   // 16
#define TILES_Y (IMG_H / TILE_H)   // 16
#define TILES_PER_B (TILES_X * TILES_Y)  // 256
#define NBLOCKS (NB * TILES_PER_B)       // 8192

#define LDSF 6144                  // 24 KB staging tile (floats)

typedef float vfloat4 __attribute__((ext_vector_type(4)));

// ws layout: ws[lin] = num of block lin, ws[NBLOCKS + lin] = den of block lin.

__global__ __launch_bounds__(256) void recon_main(
    const float* __restrict__ theta,
    const float* __restrict__ img_R,
    const float* __restrict__ img_orig,
    float* __restrict__ ws)
{
    __shared__ __align__(16) float tileLds[LDSF];
    __shared__ float snum[4];
    __shared__ float sden[4];

    // --- XCD-aware decode: same batch -> same XCD (lin%8) ---
    const int lin = blockIdx.x;        // 0..8191
    const int xcd = lin & 7;
    const int loc = lin >> 3;          // 0..1023
    const int b   = xcd * 4 + (loc >> 8);   // 0..31
    const int tile = loc & 255;        // 0..255
    const int tx = (tile & (TILES_X - 1)) * TILE_W;
    const int ty = (tile >> 4) * TILE_H;

    const int tid  = threadIdx.x;
    const int trow = tid >> 3;         // 0..31 (8 threads per tile row)
    const int tcol = (tid & 7) * 4;    // 0..28

    // --- per-batch affine (uniform across block) ---
    const float ang   = theta[b * 3 + 0];
    const float s     = theta[b * 3 + 1];
    const float shift = 100.0f * theta[b * 3 + 2];
    float sn, cs;
    sincosf(ang, &sn, &cs);
    const float alpha = s * cs;
    const float beta  = s * sn;
    const float tx_a = (1.0f - alpha) * 256.0f - beta * 256.0f + shift;
    const float ty_a = beta * 256.0f + (1.0f - alpha) * 256.0f;
    const float Cc = alpha + beta + 2.0f * tx_a / 511.0f - 1.0f;
    const float Fc = -beta + alpha + 2.0f * ty_a / 511.0f - 1.0f;
    // source coords: x = X0 + alpha*w + beta*h ; y = Y0 - beta*w + alpha*h
    const float X0 = 255.5f * (Cc + 1.0f - alpha - beta);
    const float Y0 = 255.5f * (Fc + 1.0f + beta - alpha);

    const float* orig_b = img_orig + (size_t)b * NC * PLANE;
    const float* R_b    = img_R    + (size_t)b * NC * PLANE;

    const int h  = ty + trow;
    const int w0 = tx + tcol;
    const int p0 = h * IMG_W + w0;

    const float xb = X0 + alpha * (float)w0 + beta * (float)h;
    const float yb = Y0 - beta * (float)w0 + alpha * (float)h;

    int   xi0a[4], xi1a[4], yi0a[4], yi1a[4];
    float w00[4], w10[4], w01[4], w11[4], mk[4];
    float den_acc = 0.0f;

#pragma unroll
    for (int j = 0; j < 4; ++j) {
        const float x = xb + alpha * (float)j;
        const float y = yb - beta  * (float)j;
        const float x0f = floorf(x), y0f = floorf(y);
        const float fx1 = x - x0f,  fy1 = y - y0f;
        const float fx0 = 1.0f - fx1, fy0 = 1.0f - fy1;
        const float vx0 = (x0f >=  0.0f && x0f <= 511.0f) ? 1.0f : 0.0f;
        const float vx1 = (x0f >= -1.0f && x0f <= 510.0f) ? 1.0f : 0.0f;
        const float vy0 = (y0f >=  0.0f && y0f <= 511.0f) ? 1.0f : 0.0f;
        const float vy1 = (y0f >= -1.0f && y0f <= 510.0f) ? 1.0f : 0.0f;
        xi0a[j] = (int)fminf(fmaxf(x0f,        0.0f), 511.0f);
        xi1a[j] = (int)fminf(fmaxf(x0f + 1.0f, 0.0f), 511.0f);
        yi0a[j] = (int)fminf(fmaxf(y0f,        0.0f), 511.0f);
        yi1a[j] = (int)fminf(fmaxf(y0f + 1.0f, 0.0f), 511.0f);
        w00[j] = fx0 * fy0 * vx0 * vy0;
        w10[j] = fx1 * fy0 * vx1 * vy0;
        w01[j] = fx0 * fy1 * vx0 * vy1;
        w11[j] = fx1 * fy1 * vx1 * vy1;
        mk[j]  = w00[j] + w10[j] + w01[j] + w11[j];
        den_acc += mk[j];
    }

    // --- block-uniform source bbox (extrema of affine map are at tile corners) ---
    const float fx_lo = (float)tx, fx_hi = (float)(tx + TILE_W - 1);
    const float fy_lo = (float)ty, fy_hi = (float)(ty + TILE_H - 1);
    const float cxA = X0 + alpha * fx_lo + beta * fy_lo;
    const float cxB = X0 + alpha * fx_hi + beta * fy_lo;
    const float cxC = X0 + alpha * fx_lo + beta * fy_hi;
    const float cxD = X0 + alpha * fx_hi + beta * fy_hi;
    const float cyA = Y0 - beta * fx_lo + alpha * fy_lo;
    const float cyB = Y0 - beta * fx_hi + alpha * fy_lo;
    const float cyC = Y0 - beta * fx_lo + alpha * fy_hi;
    const float cyD = Y0 - beta * fx_hi + alpha * fy_hi;
    const float min_x = fminf(fminf(cxA, cxB), fminf(cxC, cxD));
    const float max_x = fmaxf(fmaxf(cxA, cxB), fmaxf(cxC, cxD));
    const float min_y = fminf(fminf(cyA, cyB), fminf(cyC, cyD));
    const float max_y = fmaxf(fmaxf(cyA, cyB), fmaxf(cyC, cyD));

    int xlo = (int)floorf(min_x);
    int xhi = (int)floorf(max_x) + 1;
    xlo = min(max(xlo, 0), 511);
    xhi = min(max(xhi, 0), 511);
    xlo &= ~3;                          // 16B-align staging rows
    int ylo = (int)floorf(min_y);
    int yhi = (int)floorf(max_y) + 1;
    ylo = min(max(ylo, 0), 511);
    yhi = min(max(yhi, 0), 511);

    const int bw = xhi - xlo + 1;
    const int bh = yhi - ylo + 1;
    int stride = (bw + 3) & ~3;
    if (((stride >> 2) & 1) == 0) stride += 4;   // stride/4 odd: bank decorrelation
    const int nq4 = stride >> 2;
    const bool staged = (stride * bh <= LDSF) && (nq4 <= 32);

    float nrm[4] = {0.0f, 0.0f, 0.0f, 0.0f};

    if (staged) {
        int l00[4], l10[4], l01[4], l11[4];
#pragma unroll
        for (int j = 0; j < 4; ++j) {
            const int r0 = (yi0a[j] - ylo) * stride - xlo;
            const int r1 = (yi1a[j] - ylo) * stride - xlo;
            l00[j] = r0 + xi0a[j];
            l10[j] = r0 + xi1a[j];
            l01[j] = r1 + xi0a[j];
            l11[j] = r1 + xi1a[j];
        }
        const int qq  = tid & 31;           // quad within staging row
        const int r00 = tid >> 5;           // 0..7
        const int col = xlo + (qq << 2);
        const bool doload = (col <= xhi);   // implies qq < nq4

        for (int c = 0; c < NC; ++c) {
            if (c) __syncthreads();         // drain prior channel's reads
            const float* plane = orig_b + c * PLANE;
            if (doload) {
                for (int r = r00; r < bh; r += 8) {
                    const vfloat4 v = *(const vfloat4*)(plane + (ylo + r) * IMG_W + col);
                    *(vfloat4*)(&tileLds[r * stride + (qq << 2)]) = v;
                }
            }
            __syncthreads();
            const vfloat4 rv = __builtin_nontemporal_load(
                                 (const vfloat4*)(R_b + c * PLANE + p0));
            const float rj[4] = {rv.x, rv.y, rv.z, rv.w};
#pragma unroll
            for (int j = 0; j < 4; ++j) {
                const float s00 = tileLds[l00[j]];
                const float s10 = tileLds[l10[j]];
                const float s01 = tileLds[l01[j]];
                const float s11 = tileLds[l11[j]];
                const float warped = s00 * w00[j] + s10 * w10[j]
                                   + s01 * w01[j] + s11 * w11[j];
                nrm[j] += fabsf(rj[j] - warped);
            }
        }
    } else {
        // direct-gather fallback (minification blocks: little reuse anyway)
        int a0[4], a1[4], sl0[4], sl1[4];
#pragma unroll
        for (int j = 0; j < 4; ++j) {
            const int xc = min(xi0a[j], 510);
            a0[j]  = yi0a[j] * IMG_W + xc;
            a1[j]  = yi1a[j] * IMG_W + xc;
            sl0[j] = xi0a[j] - xc;
            sl1[j] = xi1a[j] - xc;
        }
#pragma unroll
        for (int c = 0; c < NC; ++c) {
            const float* plane = orig_b + c * PLANE;
            const vfloat4 rv = __builtin_nontemporal_load(
                                 (const vfloat4*)(R_b + c * PLANE + p0));
            const float rj[4] = {rv.x, rv.y, rv.z, rv.w};
#pragma unroll
            for (int j = 0; j < 4; ++j) {
                const float2 t0 = *(const float2*)(plane + a0[j]);
                const float2 t1 = *(const float2*)(plane + a1[j]);
                const float s00 = sl0[j] ? t0.y : t0.x;
                const float s10 = sl1[j] ? t0.y : t0.x;
                const float s01 = sl0[j] ? t1.y : t1.x;
                const float s11 = sl1[j] ? t1.y : t1.x;
                const float warped = s00 * w00[j] + s10 * w10[j]
                                   + s01 * w01[j] + s11 * w11[j];
                nrm[j] += fabsf(rj[j] - warped);
            }
        }
    }

    float num_acc = 0.0f;
#pragma unroll
    for (int j = 0; j < 4; ++j) num_acc += mk[j] * nrm[j];

    // --- wave (64) reduction ---
#pragma unroll
    for (int off = 32; off > 0; off >>= 1) {
        num_acc += __shfl_down(num_acc, off);
        den_acc += __shfl_down(den_acc, off);
    }

    const int wave = threadIdx.x >> 6;
    const int lane = threadIdx.x & 63;
    if (lane == 0) { snum[wave] = num_acc; sden[wave] = den_acc; }
    __syncthreads();
    if (threadIdx.x == 0) {
        ws[lin]           = snum[0] + snum[1] + snum[2] + snum[3];
        ws[NBLOCKS + lin] = sden[0] + sden[1] + sden[2] + sden[3];
    }
}

__global__ __launch_bounds__(256) void recon_final(
    const float* __restrict__ ws,
    float* __restrict__ out)
{
    __shared__ float sloss[NB];
    const int t = threadIdx.x;
    const int b = t >> 3;              // 0..31 (8 threads per batch)
    const int j = t & 7;               // 0..7

    float n = 0.0f, d = 0.0f;
    for (int k = 0; k < 32; ++k) {
        const int tile = j * 32 + k;
        const int lin  = ((b & 3) * 256 + tile) * 8 + (b >> 2);
        n += ws[lin];
        d += ws[NBLOCKS + lin];
    }
#pragma unroll
    for (int off = 4; off > 0; off >>= 1) {
        n += __shfl_down(n, off);
        d += __shfl_down(d, off);
    }
    if (j == 0) sloss[b] = 10.0f * (n + 1e-16f) / (d + 1e-16f);
    __syncthreads();
    if (t == 0) {
        float L = 0.0f;
#pragma unroll
        for (int i = 0; i < NB; ++i) L += sloss[i];
        out[0] = L * (1.0f / (float)NB);
    }
}

extern "C" void kernel_launch(void* const* d_in, const int* in_sizes, int n_in,
                              void* d_out, int out_size, void* d_ws, size_t ws_size,
                              hipStream_t stream) {
    const float* theta    = (const float*)d_in[0];
    const float* img_R    = (const float*)d_in[1];
    const float* img_orig = (const float*)d_in[2];
    float* out = (float*)d_out;
    float* ws  = (float*)d_ws;

    recon_main<<<NBLOCKS, 256, 0, stream>>>(theta, img_R, img_orig, ws);
    recon_final<<<1, 256, 0, stream>>>(ws, out);
}